// Round 1
// baseline (587.666 us; speedup 1.0000x reference)
//
#include <hip/hip_runtime.h>
#include <hip/hip_bf16.h>
#include <stdint.h>

// GnnActor fused deepset actor. INPUTS/OUTPUTS ARE FLOAT32 (reference dtype).
// v2 restructure (latency-bound fix):
//  - B operands read DIRECTLY from L2-resident bf16 weight arrays (no LDS
//    staging, no per-K-step barriers). GEMM1/GEMM2 are barrier-free dataflow.
//  - A-tile (32 x 320) staged in LDS ONCE per node; obs body staged once per
//    block; next node's A columns prefetched into registers during current
//    node's epilogue/GEMM2 (T14 async-split).
//  - 2 barriers per node (was 18).
//  - atomicAdd pooled accumulation replaced by plain stores into two half
//    buffers (one per nhalf block) summed in rho_heads; zero_pooled deleted.
// Scratch in module __device__ arrays (no d_ws use; graph-safe).

#define Bsz   8192
#define OBSW  1216      // 64 + 9*128
#define NH    256

typedef unsigned short u16;
typedef unsigned int   u32;

using bf16x8 = __attribute__((ext_vector_type(8))) short;
using f32x4  = __attribute__((ext_vector_type(4))) float;

// ---- module-scope scratch (~17.2 MB .bss) ----
__device__ u16   g_W1t[256 * 320];      // bf16(W1)^T  (N=256 rows, K=320)
__device__ u16   g_W2t[256 * 256];      // bf16(W2)^T
__device__ u16   g_Rt [256 * 256];      // bf16(Wrho)^T
__device__ u16   g_Wcat[64 * 256];      // [bf16(Wm)^T ; bf16(Ws)^T]
__device__ float g_pool2[2][Bsz * NH];  // per-nhalf pooled partials (f32)

__device__ __forceinline__ u16 f2bf(float f) {
  union { float f; u32 i; } v; v.f = f;
  u32 x = v.i;
  x += 0x7fffu + ((x >> 16) & 1u);   // RNE; values here are finite
  return (u16)(x >> 16);
}
__device__ __forceinline__ uint4 pack8(const float* f) {
  uint4 o;
  o.x = (u32)f2bf(f[0]) | ((u32)f2bf(f[1]) << 16);
  o.y = (u32)f2bf(f[2]) | ((u32)f2bf(f[3]) << 16);
  o.z = (u32)f2bf(f[4]) | ((u32)f2bf(f[5]) << 16);
  o.w = (u32)f2bf(f[6]) | ((u32)f2bf(f[7]) << 16);
  return o;
}
__device__ __forceinline__ void load8f(const float* p, float* f) {
  *(float4*)(f)     = *(const float4*)(p);
  *(float4*)(f + 4) = *(const float4*)(p + 4);
}

// ---------------- weight transpose+cast: f32 in[K][N] -> bf16 g_*[N][K] --------
// dst: 0=g_W1t 1=g_W2t 2=g_Rt 3=g_Wcat(+row_off rows)
__global__ void transpose_cast(const float* __restrict__ in, int dst,
                               int K, int N, int row_off) {
  __shared__ u16 tile[32][33];
  u16* out = (dst == 0) ? g_W1t : (dst == 1) ? g_W2t : (dst == 2) ? g_Rt : g_Wcat;
  int k0 = blockIdx.x * 32, n0 = blockIdx.y * 32;
  int c = threadIdx.x & 31, r0 = threadIdx.x >> 5;
  #pragma unroll
  for (int i = 0; i < 4; i++) {
    int r = r0 + i * 8;
    tile[r][c] = f2bf(in[(size_t)(k0 + r) * N + (n0 + c)]);
  }
  __syncthreads();
  #pragma unroll
  for (int i = 0; i < 4; i++) {
    int r = r0 + i * 8;
    out[(size_t)(n0 + r + row_off) * K + (k0 + c)] = tile[c][r];
  }
}

// gather node-n feature columns 64..319 into regs f[4][8]:
//  f[0],f[1] = object/iso node dims 0..63 / 64..127
//  f[2],f[3] = segmax over 8 edges (or iso feats) dims 0..63 / 64..127
__device__ __forceinline__ void loadA(
    int n, size_t sb, int sck,
    const float* __restrict__ obs, const float* __restrict__ ef,
    const float* __restrict__ iso, const float* __restrict__ isof,
    float f[4][8]) {
  if (n < 9) {
    const float* po = obs + sb * OBSW + 64 + (size_t)n * 128 + sck;
    load8f(po, f[0]);
    load8f(po + 64, f[1]);
    const float* base = ef + (sb * 72 + n) * 128 + sck;   // edge e = n + 9j
    load8f(base, f[2]);
    load8f(base + 64, f[3]);
    #pragma unroll
    for (int j = 1; j < 8; j++) {
      float w0[8], w1[8];
      load8f(base + (size_t)j * 1152, w0);
      load8f(base + (size_t)j * 1152 + 64, w1);
      #pragma unroll
      for (int q = 0; q < 8; q++) {
        f[2][q] = fmaxf(f[2][q], w0[q]);
        f[3][q] = fmaxf(f[3][q], w1[q]);
      }
    }
  } else {
    const float* pi = iso  + (sb * 3 + (n - 9)) * 128 + sck;
    const float* pg = isof + (sb * 3 + (n - 9)) * 128 + sck;
    load8f(pi, f[0]); load8f(pi + 64, f[1]);
    load8f(pg, f[2]); load8f(pg + 64, f[3]);
  }
}

// ---------------- fused node kernel --------------------------------------------
// grid = (Bsz/32) * 2; block (btile, nhalf) handles nodes nhalf*6..+6.
__global__ __launch_bounds__(256, 2)
void node_kernel(const float* __restrict__ obs, const float* __restrict__ ef,
                 const float* __restrict__ iso, const float* __restrict__ isof,
                 const float* __restrict__ b1, const float* __restrict__ b2) {
  // pads chosen so row-stride/4 mod 32 == 4 (same 2-way pattern as v1 kernel)
  __shared__ __attribute__((aligned(16))) u16 As[32][328];  // 32 x 320 A-tile
  __shared__ __attribute__((aligned(16))) u16 Ht[32][264];  // 32 x 256 hidden
  const int btile = blockIdx.x >> 1;
  const int nhalf = blockIdx.x & 1;
  const int b0 = btile * 32;
  const int tid = threadIdx.x;
  const int wave = tid >> 6, lane = tid & 63;
  const int nw = wave * 64, lrow = lane & 15, quad = lane >> 4;
  const int srow = tid >> 3, sck = (tid & 7) * 8;
  const size_t sb = (size_t)(b0 + srow);

  // prologue: stage obs body (cols 0..63, shared by ALL nodes) + node n0 cols
  {
    float fb[8];
    load8f(obs + sb * OBSW + sck, fb);
    *(uint4*)(&As[srow][sck]) = pack8(fb);
    float f[4][8];
    loadA(nhalf * 6, sb, sck, obs, ef, iso, isof, f);
    #pragma unroll
    for (int c = 0; c < 4; c++)
      *(uint4*)(&As[srow][(c + 1) * 64 + sck]) = pack8(f[c]);
  }
  __syncthreads();   // As(node n0) ready

  const f32x4 vzero = {0.f, 0.f, 0.f, 0.f};
  f32x4 pool[2][4];
  #pragma unroll
  for (int a = 0; a < 2; a++)
    #pragma unroll
    for (int b = 0; b < 4; b++) pool[a][b] = vzero;

  for (int nn = 0; nn < 6; nn++) {
    const int n = nhalf * 6 + nn;
    f32x4 acc[2][4];
    #pragma unroll
    for (int a = 0; a < 2; a++)
      #pragma unroll
      for (int b = 0; b < 4; b++) acc[a][b] = vzero;

    // ---- GEMM1: K=320, A from LDS, B direct from L2 — NO barriers ----------
    #pragma unroll
    for (int kc = 0; kc < 10; kc++) {
      const int kk = kc * 32 + quad * 8;
      bf16x8 af0 = *(const bf16x8*)(&As[lrow][kk]);
      bf16x8 af1 = *(const bf16x8*)(&As[16 + lrow][kk]);
      #pragma unroll
      for (int nb = 0; nb < 4; nb++) {
        bf16x8 bq = *(const bf16x8*)(g_W1t + (size_t)(nw + nb * 16 + lrow) * 320 + kk);
        acc[0][nb] = __builtin_amdgcn_mfma_f32_16x16x32_bf16(af0, bq, acc[0][nb], 0, 0, 0);
        acc[1][nb] = __builtin_amdgcn_mfma_f32_16x16x32_bf16(af1, bq, acc[1][nb], 0, 0, 0);
      }
    }

    // prefetch next node's A columns (HBM) — latency hides under epi1+GEMM2
    float fnext[4][8];
    if (nn < 5) loadA(n + 1, sb, sck, obs, ef, iso, isof, fnext);

    // epilogue 1: Ht = bf16(relu(acc + b1))  (D: row=quad*4+i, col=lane&15)
    #pragma unroll
    for (int nb = 0; nb < 4; nb++) {
      int col = nw + nb * 16 + lrow;
      float bv = b1[col];
      #pragma unroll
      for (int mb = 0; mb < 2; mb++)
        #pragma unroll
        for (int i = 0; i < 4; i++)
          Ht[mb * 16 + quad * 4 + i][col] = f2bf(fmaxf(acc[mb][nb][i] + bv, 0.f));
    }
    __syncthreads();   // S1: Ht visible; everyone's As reads (GEMM1) done

    // write next node's A-tile (safe: all GEMM1 reads retired at S1)
    if (nn < 5) {
      #pragma unroll
      for (int c = 0; c < 4; c++)
        *(uint4*)(&As[srow][(c + 1) * 64 + sck]) = pack8(fnext[c]);
    }

    #pragma unroll
    for (int a = 0; a < 2; a++)
      #pragma unroll
      for (int b = 0; b < 4; b++) acc[a][b] = vzero;

    // ---- GEMM2: K=256, A from Ht, B direct from L2 — NO barriers -----------
    #pragma unroll
    for (int kc = 0; kc < 8; kc++) {
      const int kk = kc * 32 + quad * 8;
      bf16x8 af0 = *(const bf16x8*)(&Ht[lrow][kk]);
      bf16x8 af1 = *(const bf16x8*)(&Ht[16 + lrow][kk]);
      #pragma unroll
      for (int nb = 0; nb < 4; nb++) {
        bf16x8 bq = *(const bf16x8*)(g_W2t + (size_t)(nw + nb * 16 + lrow) * 256 + kk);
        acc[0][nb] = __builtin_amdgcn_mfma_f32_16x16x32_bf16(af0, bq, acc[0][nb], 0, 0, 0);
        acc[1][nb] = __builtin_amdgcn_mfma_f32_16x16x32_bf16(af1, bq, acc[1][nb], 0, 0, 0);
      }
    }
    // epilogue 2: pool += relu(acc + b2)
    #pragma unroll
    for (int nb = 0; nb < 4; nb++) {
      int col = nw + nb * 16 + lrow;
      float bv = b2[col];
      #pragma unroll
      for (int mb = 0; mb < 2; mb++)
        #pragma unroll
        for (int i = 0; i < 4; i++)
          pool[mb][nb][i] += fmaxf(acc[mb][nb][i] + bv, 0.f);
    }
    __syncthreads();   // S2: As(n+1) visible; Ht reads (GEMM2) done
  }

  // plain stores — each element written once by this block (no atomics)
  float* op = g_pool2[nhalf];
  #pragma unroll
  for (int nb = 0; nb < 4; nb++) {
    int col = nw + nb * 16 + lrow;
    #pragma unroll
    for (int mb = 0; mb < 2; mb++)
      #pragma unroll
      for (int i = 0; i < 4; i++) {
        int row = b0 + mb * 16 + quad * 4 + i;
        op[(size_t)row * NH + col] = pool[mb][nb][i];
      }
  }
}

// ---------------- rho + heads ---------------------------------------------------
// grid = Bsz/32. sum(g_pool2) -> GEMM3(relu,br) -> heads(N=64) -> clip -> out.
__global__ __launch_bounds__(256)
void rho_heads(const float* __restrict__ br, const float* __restrict__ bm,
               const float* __restrict__ bs, float* __restrict__ out) {
  __shared__ __attribute__((aligned(16))) u16 As2[32][264];
  const int b0 = blockIdx.x * 32;
  const int tid = threadIdx.x;
  const int wave = tid >> 6, lane = tid & 63;
  const int nw = wave * 64, lrow = lane & 15, quad = lane >> 4;
  const int srow = tid >> 3, sck = (tid & 7) * 8;

  // stage pooled = half0 + half1 (f32) -> bf16 A-tile 32x256
  #pragma unroll
  for (int c4 = 0; c4 < 4; c4++) {
    int col = c4 * 64 + sck;
    float f0[8], f1[8];
    load8f(g_pool2[0] + (size_t)(b0 + srow) * NH + col, f0);
    load8f(g_pool2[1] + (size_t)(b0 + srow) * NH + col, f1);
    #pragma unroll
    for (int q = 0; q < 8; q++) f0[q] += f1[q];
    *(uint4*)(&As2[srow][col]) = pack8(f0);
  }
  __syncthreads();

  const f32x4 vzero = {0.f, 0.f, 0.f, 0.f};
  f32x4 acc[2][4];
  #pragma unroll
  for (int a = 0; a < 2; a++)
    #pragma unroll
    for (int b = 0; b < 4; b++) acc[a][b] = vzero;

  // GEMM3: K=256, B direct from g_Rt — no inner barriers
  #pragma unroll
  for (int kc = 0; kc < 8; kc++) {
    const int kk = kc * 32 + quad * 8;
    bf16x8 af0 = *(const bf16x8*)(&As2[lrow][kk]);
    bf16x8 af1 = *(const bf16x8*)(&As2[16 + lrow][kk]);
    #pragma unroll
    for (int nb = 0; nb < 4; nb++) {
      bf16x8 bq = *(const bf16x8*)(g_Rt + (size_t)(nw + nb * 16 + lrow) * 256 + kk);
      acc[0][nb] = __builtin_amdgcn_mfma_f32_16x16x32_bf16(af0, bq, acc[0][nb], 0, 0, 0);
      acc[1][nb] = __builtin_amdgcn_mfma_f32_16x16x32_bf16(af1, bq, acc[1][nb], 0, 0, 0);
    }
  }
  __syncthreads();   // As2 reads done

  // r = bf16(relu(acc + br)) -> back into As2
  #pragma unroll
  for (int nb = 0; nb < 4; nb++) {
    int col = nw + nb * 16 + lrow;
    float bv = br[col];
    #pragma unroll
    for (int mb = 0; mb < 2; mb++)
      #pragma unroll
      for (int i = 0; i < 4; i++)
        As2[mb * 16 + quad * 4 + i][col] = f2bf(fmaxf(acc[mb][nb][i] + bv, 0.f));
  }
  __syncthreads();   // r visible

  // heads: N=64 (mean|log_std); wave w owns 16-col tile w. B direct from g_Wcat.
  f32x4 acc2[2] = {vzero, vzero};
  #pragma unroll
  for (int kc = 0; kc < 8; kc++) {
    const int kk = kc * 32 + quad * 8;
    bf16x8 af0 = *(const bf16x8*)(&As2[lrow][kk]);
    bf16x8 af1 = *(const bf16x8*)(&As2[16 + lrow][kk]);
    bf16x8 bq  = *(const bf16x8*)(g_Wcat + (size_t)(wave * 16 + lrow) * 256 + kk);
    acc2[0] = __builtin_amdgcn_mfma_f32_16x16x32_bf16(af0, bq, acc2[0], 0, 0, 0);
    acc2[1] = __builtin_amdgcn_mfma_f32_16x16x32_bf16(af1, bq, acc2[1], 0, 0, 0);
  }

  int j = wave * 16 + lrow;
  #pragma unroll
  for (int mb = 0; mb < 2; mb++) {
    #pragma unroll
    for (int i = 0; i < 4; i++) {
      int b = b0 + mb * 16 + quad * 4 + i;
      if (j < 32) {
        out[(size_t)b * 32 + j] = acc2[mb][i] + bm[j];
      } else {
        float v = acc2[mb][i] + bs[j - 32];
        v = fminf(fmaxf(v, -20.f), 2.f);
        out[(size_t)Bsz * 32 + (size_t)b * 32 + (j - 32)] = v;
      }
    }
  }
}

extern "C" void kernel_launch(void* const* d_in, const int* in_sizes, int n_in,
                              void* d_out, int out_size, void* d_ws, size_t ws_size,
                              hipStream_t stream) {
  const float* obs  = (const float*)d_in[0];
  const float* ef   = (const float*)d_in[1];
  // d_in[2] = edges_to (int32): tile(arange(9),8) -> edge e feeds node e%9
  const float* iso  = (const float*)d_in[3];
  const float* isof = (const float*)d_in[4];
  const float* W1   = (const float*)d_in[5];
  const float* b1   = (const float*)d_in[6];
  const float* W2   = (const float*)d_in[7];
  const float* b2   = (const float*)d_in[8];
  const float* Wr   = (const float*)d_in[9];
  const float* br   = (const float*)d_in[10];
  const float* Wm   = (const float*)d_in[11];
  const float* bm   = (const float*)d_in[12];
  const float* Wsg  = (const float*)d_in[13];
  const float* bs   = (const float*)d_in[14];
  float* out = (float*)d_out;
  (void)d_ws; (void)ws_size;

  transpose_cast<<<dim3(10, 8), 256, 0, stream>>>(W1, 0, 320, 256, 0);
  transpose_cast<<<dim3(8, 8), 256, 0, stream>>>(W2, 1, 256, 256, 0);
  transpose_cast<<<dim3(8, 8), 256, 0, stream>>>(Wr, 2, 256, 256, 0);
  transpose_cast<<<dim3(8, 1), 256, 0, stream>>>(Wm, 3, 256, 32, 0);
  transpose_cast<<<dim3(8, 1), 256, 0, stream>>>(Wsg, 3, 256, 32, 32);

  node_kernel<<<(Bsz / 32) * 2, 256, 0, stream>>>(obs, ef, iso, isof, b1, b2);
  rho_heads<<<Bsz / 32, 256, 0, stream>>>(br, bm, bs, out);
}